// Round 2
// baseline (215.254 us; speedup 1.0000x reference)
//
#include <hip/hip_runtime.h>
#include <hip/hip_bf16.h>

#define S_LEN 2048
#define D_DIM 512
#define K_NB  64

// ---------------------------------------------------------------------------
// Cantor measure, replicating the JAX fp32 pipeline bit-for-bit where possible.
// All ops except exp are exactly-rounded IEEE fp32 (mul/fmod/sub/div-pow2/add).
// exp computed in double then rounded -> correctly-rounded fp32 exp.
// ---------------------------------------------------------------------------
__global__ void cantor_kernel(float* __restrict__ cmf) {
    int s = blockIdx.x * blockDim.x + threadIdx.x;
    if (s >= S_LEN) return;
    float pos = ((float)s + 0.5f) * (1.0f / 2048.0f);  // exact (power of two)
    float cm = 0.0f;
    float scale = 1.0f, lvlw = 1.0f;
    #pragma unroll
    for (int k = 1; k <= 5; ++k) {
        scale *= 3.0f;   // 3,9,27,81,243 exact
        lvlw  *= 0.5f;   // 0.5^k exact
        float y = fmodf(pos * scale, 3.0f);   // positive args -> exact
        float d0 = y - 0.5f, d1 = y - 1.5f, d2 = y - 2.5f;
        // /(TAU+1e-10): fp32(0.25+1e-10)==0.25; /0.25 == *4 (exact)
        float l0 = -(d0 * d0) * 4.0f;
        float l1 = -(d1 * d1) * 4.0f;
        float l2 = -(d2 * d2) * 4.0f;
        float m = fmaxf(l0, fmaxf(l1, l2));
        float e0 = (float)exp((double)(l0 - m));
        float e1 = (float)exp((double)(l1 - m));
        float e2 = (float)exp((double)(l2 - m));
        float sum = (e0 + e1) + e2;
        float p1 = e1 / sum;
        float p2 = e2 / sum;
        float bits = p2 + 0.5f * p1;   // ALPHA*p1 exact
        cm += bits * lvlw;             // bits*lvlw exact
    }
    cmf[s] = cm;
}

// ---------------------------------------------------------------------------
// Exact-equality grouping: softmax weights are exactly 1/n over the first
// min(n,64) indices with cm[j]==cm[s] (lax.top_k stable tie-break), 0 else
// (fp32 exp underflow: logit gap >= 2e7 >> 88).
// ---------------------------------------------------------------------------
__global__ void group_kernel(const float* __restrict__ cmf,
                             int* __restrict__ routes,
                             int* __restrict__ counts) {
    int s = blockIdx.x * blockDim.x + threadIdx.x;
    if (s >= S_LEN) return;
    float v = cmf[s];
    int n = 0;
    for (int j = 0; j < S_LEN; ++j) {
        if (cmf[j] == v) {
            if (n < K_NB) routes[s * K_NB + n] = j;
            ++n;
        }
    }
    counts[s] = n < K_NB ? n : K_NB;
}

// ---------------------------------------------------------------------------
// fused[b,s,:] = (1/n) * sum_{k<n} h[b, routes[s,k], :]   (usually a copy)
// ---------------------------------------------------------------------------
__global__ void fuse_kernel(const float* __restrict__ h,
                            const int* __restrict__ routes,
                            const int* __restrict__ counts,
                            float* __restrict__ fused) {
    int row = blockIdx.x;             // b*2048 + s
    int s = row & (S_LEN - 1);
    int b = row >> 11;
    int n = counts[s];
    int d = threadIdx.x * 4;
    const int* rt = routes + s * K_NB;
    float4 acc = make_float4(0.f, 0.f, 0.f, 0.f);
    for (int k = 0; k < n; ++k) {
        int j = rt[k];
        const float4 hv = *(const float4*)&h[((size_t)(b * S_LEN + j)) * D_DIM + d];
        acc.x += hv.x; acc.y += hv.y; acc.z += hv.z; acc.w += hv.w;
    }
    float inv = 1.0f / (float)n;
    float4 o = make_float4(acc.x * inv, acc.y * inv, acc.z * inv, acc.w * inv);
    *(float4*)&fused[(size_t)row * D_DIM + d] = o;
}

// ---------------------------------------------------------------------------
// fp32 tiled GEMM: C[M,512] = A[M,512] @ B[512,512] + bias
// EPI==0: store fp32 to Cf.  EPI==1: Cf = X + C  (residual epilogue, f32 out)
// 64x64 tile, 256 threads, 4x4 per thread, BK=16.
// ---------------------------------------------------------------------------
template <int EPI>
__global__ __launch_bounds__(256) void gemm512(const float* __restrict__ A,
                                               const float* __restrict__ B,
                                               const float* __restrict__ bias,
                                               const float* __restrict__ X,
                                               float* __restrict__ Cf) {
    const int N = 512, K = 512;
    __shared__ float As[64][16];
    __shared__ float Bs[16][64];
    int tid = threadIdx.x;
    int tx = tid & 15, ty = tid >> 4;
    int bm = blockIdx.y, bn = blockIdx.x;
    const float* Ab = A + (size_t)(bm * 64) * K;
    const float* Bb = B + bn * 64;
    int ar = tid >> 2, ac = (tid & 3) * 4;
    int br = tid >> 4, bc = (tid & 15) * 4;
    float acc[4][4] = {};
    for (int k0 = 0; k0 < K; k0 += 16) {
        float4 a4 = *(const float4*)(Ab + (size_t)ar * K + k0 + ac);
        float4 b4 = *(const float4*)(Bb + (size_t)(k0 + br) * N + bc);
        *(float4*)&As[ar][ac] = a4;
        *(float4*)&Bs[br][bc] = b4;
        __syncthreads();
        #pragma unroll
        for (int kk = 0; kk < 16; ++kk) {
            float av[4];
            #pragma unroll
            for (int i = 0; i < 4; ++i) av[i] = As[ty * 4 + i][kk];
            float4 bv = *(const float4*)&Bs[kk][tx * 4];
            #pragma unroll
            for (int i = 0; i < 4; ++i) {
                acc[i][0] += av[i] * bv.x;
                acc[i][1] += av[i] * bv.y;
                acc[i][2] += av[i] * bv.z;
                acc[i][3] += av[i] * bv.w;
            }
        }
        __syncthreads();
    }
    #pragma unroll
    for (int i = 0; i < 4; ++i) {
        int row = bm * 64 + ty * 4 + i;
        #pragma unroll
        for (int j = 0; j < 4; ++j) {
            int col = bn * 64 + tx * 4 + j;
            float v = acc[i][j] + bias[col];
            if (EPI == 0) {
                Cf[(size_t)row * N + col] = v;
            } else {
                Cf[(size_t)row * N + col] = X[(size_t)row * N + col] + v;
            }
        }
    }
}

extern "C" void kernel_launch(void* const* d_in, const int* in_sizes, int n_in,
                              void* d_out, int out_size, void* d_ws, size_t ws_size,
                              hipStream_t stream) {
    const float* x     = (const float*)d_in[0];   // [2,2048,512]
    const float* W_in  = (const float*)d_in[1];   // [512,512]
    const float* b_in  = (const float*)d_in[2];   // [512]
    const float* W_out = (const float*)d_in[3];   // [512,512]
    const float* b_out = (const float*)d_in[4];   // [512]
    float* out = (float*)d_out;                   // [2,2048,512] float32

    char* ws = (char*)d_ws;
    float* cmf    = (float*)ws;                             // 2048 f32
    int*   counts = (int*)(ws + 2048 * 4);                  // 2048 i32
    int*   routes = (int*)(ws + 2048 * 8);                  // 2048*64 i32
    float* h      = (float*)(ws + 2048 * 8 + 2048 * 64 * 4);// 4096*512 f32
    float* fused  = h + (size_t)4096 * 512;                 // 4096*512 f32

    cantor_kernel<<<8, 256, 0, stream>>>(cmf);
    group_kernel<<<8, 256, 0, stream>>>(cmf, routes, counts);
    gemm512<0><<<dim3(8, 64), 256, 0, stream>>>(x, W_in, b_in, nullptr, h);
    fuse_kernel<<<4096, 128, 0, stream>>>(h, routes, counts, fused);
    gemm512<1><<<dim3(8, 64), 256, 0, stream>>>(fused, W_out, b_out, x, out);
}

// Round 3
// 157.100 us; speedup vs baseline: 1.3702x; 1.3702x over previous
//
#include <hip/hip_runtime.h>
#include <hip/hip_bf16.h>

#define S_LEN 2048
#define D_DIM 512
#define K_NB  64

// ---------------------------------------------------------------------------
// Cantor measure, replicating the JAX fp32 pipeline bit-for-bit where possible.
// ---------------------------------------------------------------------------
__global__ void cantor_kernel(float* __restrict__ cmf) {
    int s = blockIdx.x * blockDim.x + threadIdx.x;
    if (s >= S_LEN) return;
    float pos = ((float)s + 0.5f) * (1.0f / 2048.0f);  // exact (power of two)
    float cm = 0.0f;
    float scale = 1.0f, lvlw = 1.0f;
    #pragma unroll
    for (int k = 1; k <= 5; ++k) {
        scale *= 3.0f;   // 3,9,27,81,243 exact
        lvlw  *= 0.5f;   // 0.5^k exact
        float y = fmodf(pos * scale, 3.0f);   // positive args -> exact
        float d0 = y - 0.5f, d1 = y - 1.5f, d2 = y - 2.5f;
        float l0 = -(d0 * d0) * 4.0f;        // /(0.25+1e-10) == *4 in fp32
        float l1 = -(d1 * d1) * 4.0f;
        float l2 = -(d2 * d2) * 4.0f;
        float m = fmaxf(l0, fmaxf(l1, l2));
        float e0 = (float)exp((double)(l0 - m));
        float e1 = (float)exp((double)(l1 - m));
        float e2 = (float)exp((double)(l2 - m));
        float sum = (e0 + e1) + e2;
        float p1 = e1 / sum;
        float p2 = e2 / sum;
        float bits = p2 + 0.5f * p1;
        cm += bits * lvlw;
    }
    cmf[s] = cm;
}

// ---------------------------------------------------------------------------
// Exact-equality grouping, LDS-staged: weights are exactly 1/n over the first
// min(n,64) indices with cm[j]==cm[s] (lax.top_k stable tie-break), 0 else
// (fp32 exp underflow: logit gap >= 2e7 >> 88).
// 32 blocks x 64 threads; each block stages all 2048 cm in LDS (8 KB).
// ---------------------------------------------------------------------------
__global__ __launch_bounds__(64) void group_kernel(const float* __restrict__ cmf,
                                                   int* __restrict__ routes,
                                                   int* __restrict__ counts) {
    __shared__ float lds[S_LEN];
    int tid = threadIdx.x;
    for (int i = tid; i < S_LEN / 4; i += 64)
        *(float4*)&lds[i * 4] = *(const float4*)&cmf[i * 4];
    __syncthreads();
    int s = blockIdx.x * 64 + tid;
    float v = lds[s];
    int n = 0;
    int* rt = routes + s * K_NB;
    #pragma unroll 4
    for (int j = 0; j < S_LEN; j += 4) {
        float4 c = *(const float4*)&lds[j];   // wave-uniform addr -> broadcast
        if (c.x == v) { if (n < K_NB) rt[n] = j;     ++n; }
        if (c.y == v) { if (n < K_NB) rt[n] = j + 1; ++n; }
        if (c.z == v) { if (n < K_NB) rt[n] = j + 2; ++n; }
        if (c.w == v) { if (n < K_NB) rt[n] = j + 3; ++n; }
    }
    counts[s] = n < K_NB ? n : K_NB;
}

// ---------------------------------------------------------------------------
// fp32 tiled GEMM: C[M,512] = A[M,512] @ B[512,512] + bias
// EPI==0: A read directly (A = x), store fp32 to Cf.
// EPI==1: A row = (1/n) * sum_{k<n} h[b, routes[s,k], :]  (gather-average,
//         fused former fuse_kernel), store Cf = X + C (residual).
// 64x64 tile, 256 threads, 4x4 per thread, BK=16.
// ---------------------------------------------------------------------------
template <int EPI>
__global__ __launch_bounds__(256) void gemm512(const float* __restrict__ A,
                                               const float* __restrict__ B,
                                               const float* __restrict__ bias,
                                               const float* __restrict__ X,
                                               float* __restrict__ Cf,
                                               const int* __restrict__ routes,
                                               const int* __restrict__ counts) {
    const int N = 512, K = 512;
    __shared__ float As[64][16];
    __shared__ float Bs[16][64];
    int tid = threadIdx.x;
    int tx = tid & 15, ty = tid >> 4;
    int bm = blockIdx.y, bn = blockIdx.x;
    const float* Bb = B + bn * 64;
    int ar = tid >> 2, ac = (tid & 3) * 4;
    int br = tid >> 4, bc = (tid & 15) * 4;

    // Per-thread A-row info (each thread always loads the same tile row `ar`).
    int grow = bm * 64 + ar;                  // global row in [0,4096)
    const float* Arow;                        // direct row (EPI==0)
    const float* Abatch;                      // batch base (EPI==1)
    int gn = 1; const int* grt = nullptr; float ginv = 1.0f;
    if (EPI == 0) {
        Arow = A + (size_t)grow * K;
    } else {
        int gs = grow & (S_LEN - 1), gb = grow >> 11;
        gn = counts[gs];
        grt = routes + gs * K_NB;
        ginv = 1.0f / (float)gn;
        Abatch = A + ((size_t)gb * S_LEN) * K;
    }

    float acc[4][4] = {};
    for (int k0 = 0; k0 < K; k0 += 16) {
        float4 a4;
        if (EPI == 0) {
            a4 = *(const float4*)(Arow + k0 + ac);
        } else {
            a4 = make_float4(0.f, 0.f, 0.f, 0.f);
            for (int t = 0; t < gn; ++t) {
                const float4 hv = *(const float4*)(Abatch + (size_t)grt[t] * K + k0 + ac);
                a4.x += hv.x; a4.y += hv.y; a4.z += hv.z; a4.w += hv.w;
            }
            a4.x *= ginv; a4.y *= ginv; a4.z *= ginv; a4.w *= ginv;
        }
        float4 b4 = *(const float4*)(Bb + (size_t)(k0 + br) * N + bc);
        *(float4*)&As[ar][ac] = a4;
        *(float4*)&Bs[br][bc] = b4;
        __syncthreads();
        #pragma unroll
        for (int kk = 0; kk < 16; ++kk) {
            float av[4];
            #pragma unroll
            for (int i = 0; i < 4; ++i) av[i] = As[ty * 4 + i][kk];
            float4 bv = *(const float4*)&Bs[kk][tx * 4];
            #pragma unroll
            for (int i = 0; i < 4; ++i) {
                acc[i][0] += av[i] * bv.x;
                acc[i][1] += av[i] * bv.y;
                acc[i][2] += av[i] * bv.z;
                acc[i][3] += av[i] * bv.w;
            }
        }
        __syncthreads();
    }
    #pragma unroll
    for (int i = 0; i < 4; ++i) {
        int row = bm * 64 + ty * 4 + i;
        #pragma unroll
        for (int j = 0; j < 4; ++j) {
            int col = bn * 64 + tx * 4 + j;
            float v = acc[i][j] + bias[col];
            if (EPI == 0) {
                Cf[(size_t)row * N + col] = v;
            } else {
                Cf[(size_t)row * N + col] = X[(size_t)row * N + col] + v;
            }
        }
    }
}

extern "C" void kernel_launch(void* const* d_in, const int* in_sizes, int n_in,
                              void* d_out, int out_size, void* d_ws, size_t ws_size,
                              hipStream_t stream) {
    const float* x     = (const float*)d_in[0];   // [2,2048,512]
    const float* W_in  = (const float*)d_in[1];   // [512,512]
    const float* b_in  = (const float*)d_in[2];   // [512]
    const float* W_out = (const float*)d_in[3];   // [512,512]
    const float* b_out = (const float*)d_in[4];   // [512]
    float* out = (float*)d_out;                   // [2,2048,512] float32

    char* ws = (char*)d_ws;
    float* cmf    = (float*)ws;                             // 2048 f32
    int*   counts = (int*)(ws + 2048 * 4);                  // 2048 i32
    int*   routes = (int*)(ws + 2048 * 8);                  // 2048*64 i32
    float* h      = (float*)(ws + 2048 * 8 + 2048 * 64 * 4);// 4096*512 f32

    cantor_kernel<<<8, 256, 0, stream>>>(cmf);
    group_kernel<<<32, 64, 0, stream>>>(cmf, routes, counts);
    gemm512<0><<<dim3(8, 64), 256, 0, stream>>>(x, W_in, b_in, nullptr, h,
                                                nullptr, nullptr);
    gemm512<1><<<dim3(8, 64), 256, 0, stream>>>(h, W_out, b_out, x, out,
                                                routes, counts);
}

// Round 4
// 54.490 us; speedup vs baseline: 3.9503x; 2.8831x over previous
//
#include <hip/hip_runtime.h>
#include <hip/hip_bf16.h>

#define S_LEN 2048
#define D_DIM 512
#define K_NB  64
#define BM 128
#define BN 128
#define BK 64

typedef __attribute__((ext_vector_type(8))) short bf16x8;
typedef __attribute__((ext_vector_type(4))) float f32x4;
typedef __attribute__((ext_vector_type(4))) unsigned int u32x4;

__device__ inline unsigned short f2b(float f) {
    unsigned u = __builtin_bit_cast(unsigned, f);
    return (unsigned short)((u + 0x7FFFu + ((u >> 16) & 1u)) >> 16);  // RNE
}
__device__ inline float b2f(unsigned short s) {
    return __builtin_bit_cast(float, (unsigned)s << 16);
}

// ---------------------------------------------------------------------------
// Cantor measure, fp32-faithful (exp via double = correctly rounded).
// ---------------------------------------------------------------------------
__global__ void cantor_kernel(float* __restrict__ cmf) {
    int s = blockIdx.x * blockDim.x + threadIdx.x;
    if (s >= S_LEN) return;
    float pos = ((float)s + 0.5f) * (1.0f / 2048.0f);
    float cm = 0.0f, scale = 1.0f, lvlw = 1.0f;
    #pragma unroll
    for (int k = 1; k <= 5; ++k) {
        scale *= 3.0f; lvlw *= 0.5f;
        float y = fmodf(pos * scale, 3.0f);
        float d0 = y - 0.5f, d1 = y - 1.5f, d2 = y - 2.5f;
        float l0 = -(d0 * d0) * 4.0f;   // /(0.25+1e-10) == *4 in fp32
        float l1 = -(d1 * d1) * 4.0f;
        float l2 = -(d2 * d2) * 4.0f;
        float m = fmaxf(l0, fmaxf(l1, l2));
        float e0 = (float)exp((double)(l0 - m));
        float e1 = (float)exp((double)(l1 - m));
        float e2 = (float)exp((double)(l2 - m));
        float sum = (e0 + e1) + e2;
        float p1 = e1 / sum, p2 = e2 / sum;
        cm += (p2 + 0.5f * p1) * lvlw;
    }
    cmf[s] = cm;
}

// ---------------------------------------------------------------------------
// Wave-parallel exact-equality grouping. Weights are exactly 1/n over the
// first min(n,64) j with cm[j]==cm[s] (fp32 exp underflow kills all others;
// lax.top_k stable tie-break = ascending j). One wave per s; ballot+prefix
// preserves ascending order.
// ---------------------------------------------------------------------------
__global__ __launch_bounds__(64) void group_kernel(const float* __restrict__ cmf,
                                                   int* __restrict__ routes,
                                                   int* __restrict__ counts) {
    int s = blockIdx.x;
    int lane = threadIdx.x;
    float v = cmf[s];
    int n = 0;
    int* rt = routes + s * K_NB;
    for (int j0 = 0; j0 < S_LEN; j0 += 64) {
        float c = cmf[j0 + lane];
        bool m = (c == v);
        unsigned long long mask = __ballot(m);
        if (m) {
            int idx = n + __popcll(mask & ((1ull << lane) - 1ull));
            if (idx < K_NB) rt[idx] = j0 + lane;
        }
        n += __popcll(mask);
    }
    if (lane == 0) counts[s] = n < K_NB ? n : K_NB;
}

// ---------------------------------------------------------------------------
// W[512][512] fp32 -> Wt[n][k] bf16 (transpose + convert). Reads coalesced.
// ---------------------------------------------------------------------------
__global__ __launch_bounds__(256) void wt_kernel(const float* __restrict__ W,
                                                 unsigned short* __restrict__ Wt) {
    int t = blockIdx.x * 256 + threadIdx.x;   // 32768 threads
    int n = t & 511, kc = (t >> 9) * 8;
    unsigned short tmp[8];
    #pragma unroll
    for (int j = 0; j < 8; ++j) tmp[j] = f2b(W[(size_t)(kc + j) * 512 + n]);
    *(u32x4*)(Wt + (size_t)n * 512 + kc) = *(u32x4*)tmp;
}

// ---------------------------------------------------------------------------
// bf16 MFMA GEMM, 128x128 tile, BK=64, 4 waves, XOR-swizzled LDS (T2).
// EPI==0: A = x (fp32, converted on the fly);  out Hb = bf16(A@W + bias)
// EPI==1: A row = avg of routed h rows (bf16 gather, n==1 fast path);
//         out Out = X + (A@W + bias)  fp32
// Frag layout (m89/m91-verified): A/B row|col=lane&15, k=(lane>>4)*8+j;
// D row=(lane>>4)*4+r, col=lane&15.
// ---------------------------------------------------------------------------
template <int EPI>
__global__ __launch_bounds__(256) void gemm_mfma(
    const float* __restrict__ Af, const unsigned short* __restrict__ Ab,
    const unsigned short* __restrict__ Bt, const float* __restrict__ bias,
    const float* __restrict__ X, unsigned short* __restrict__ Hb,
    float* __restrict__ Out,
    const int* __restrict__ routes, const int* __restrict__ counts) {
    __shared__ char lds[2 * BM * BK * 2];   // A 16KB | B 16KB
    char* As = lds;
    char* Bs = lds + BM * BK * 2;
    const int tid = threadIdx.x;
    const int bn = blockIdx.x, bm = blockIdx.y;
    const int wid = tid >> 6, lane = tid & 63;
    const int wr = wid >> 1, wc = wid & 1;
    const int l15 = lane & 15, l4 = lane >> 4;

    const int srow = tid >> 1;          // staged row 0..127
    const int skh = (tid & 1) * 32;     // k-half (elements)

    // byte offset in a [128][64] bf16 tile, XOR-swizzled (16B slot x row&7)
    auto aoff = [](int row, int kb) -> int {
        int o = row * 128 + kb * 2;
        return o ^ ((row & 7) << 4);
    };

    const int grow = bm * BM + srow;
    const float* arow_f = nullptr;
    int gn = 1; const int* grt = nullptr; float ginv = 1.0f; size_t hbase = 0;
    if (EPI == 0) {
        arow_f = Af + (size_t)grow * 512;
    } else {
        int gs = grow & (S_LEN - 1), gb = grow >> 11;
        gn = counts[gs];
        grt = routes + gs * K_NB;
        ginv = 1.0f / (float)gn;
        hbase = (size_t)gb * S_LEN * 512;
    }
    const unsigned short* brow = Bt + (size_t)(bn * BN + srow) * 512 + skh;

    f32x4 acc[4][4] = {};

    for (int k0 = 0; k0 < 512; k0 += BK) {
        // ---- stage A tile ----
        if (EPI == 0) {
            const float* p = arow_f + k0 + skh;
            unsigned short tmp[32];
            #pragma unroll
            for (int i = 0; i < 8; ++i) {
                float4 v = *(const float4*)(p + i * 4);
                tmp[i*4+0] = f2b(v.x); tmp[i*4+1] = f2b(v.y);
                tmp[i*4+2] = f2b(v.z); tmp[i*4+3] = f2b(v.w);
            }
            #pragma unroll
            for (int i = 0; i < 4; ++i)
                *(u32x4*)(As + aoff(srow, skh + i * 8)) = *(u32x4*)&tmp[i * 8];
        } else {
            if (gn == 1) {   // route[0] == self: bitwise copy
                const unsigned short* p = Ab + (size_t)grow * 512 + k0 + skh;
                #pragma unroll
                for (int i = 0; i < 4; ++i)
                    *(u32x4*)(As + aoff(srow, skh + i * 8)) = *(const u32x4*)(p + i * 8);
            } else {
                float av[32] = {};
                for (int e = 0; e < gn; ++e) {
                    const unsigned short* p = Ab + hbase + (size_t)grt[e] * 512 + k0 + skh;
                    #pragma unroll
                    for (int i = 0; i < 32; i += 8) {
                        u32x4 u = *(const u32x4*)(p + i);
                        #pragma unroll
                        for (int q = 0; q < 4; ++q) {
                            unsigned w = u[q];
                            av[i + q*2 + 0] += __builtin_bit_cast(float, w << 16);
                            av[i + q*2 + 1] += __builtin_bit_cast(float, w & 0xFFFF0000u);
                        }
                    }
                }
                unsigned short tmp[32];
                #pragma unroll
                for (int i = 0; i < 32; ++i) tmp[i] = f2b(av[i] * ginv);
                #pragma unroll
                for (int i = 0; i < 4; ++i)
                    *(u32x4*)(As + aoff(srow, skh + i * 8)) = *(u32x4*)&tmp[i * 8];
            }
        }
        // ---- stage B tile (pre-transposed bf16 [n][k]) ----
        {
            const unsigned short* p = brow + k0;
            #pragma unroll
            for (int i = 0; i < 4; ++i)
                *(u32x4*)(Bs + aoff(srow, skh + i * 8)) = *(const u32x4*)(p + i * 8);
        }
        __syncthreads();
        // ---- compute ----
        #pragma unroll
        for (int kk = 0; kk < 2; ++kk) {
            const int kb = kk * 32 + l4 * 8;
            bf16x8 af[4], bg[4];
            #pragma unroll
            for (int m = 0; m < 4; ++m)
                af[m] = *(bf16x8*)(As + aoff(wr * 64 + m * 16 + l15, kb));
            #pragma unroll
            for (int n = 0; n < 4; ++n)
                bg[n] = *(bf16x8*)(Bs + aoff(wc * 64 + n * 16 + l15, kb));
            #pragma unroll
            for (int m = 0; m < 4; ++m)
                #pragma unroll
                for (int n = 0; n < 4; ++n)
                    acc[m][n] = __builtin_amdgcn_mfma_f32_16x16x32_bf16(
                        af[m], bg[n], acc[m][n], 0, 0, 0);
        }
        __syncthreads();
    }

    // ---- epilogue ----
    float bv[4];
    #pragma unroll
    for (int n = 0; n < 4; ++n) bv[n] = bias[bn * BN + wc * 64 + n * 16 + l15];
    #pragma unroll
    for (int m = 0; m < 4; ++m) {
        #pragma unroll
        for (int r = 0; r < 4; ++r) {
            int row = bm * BM + wr * 64 + m * 16 + l4 * 4 + r;
            #pragma unroll
            for (int n = 0; n < 4; ++n) {
                int col = bn * BN + wc * 64 + n * 16 + l15;
                float v = acc[m][n][r] + bv[n];
                if (EPI == 0)
                    Hb[(size_t)row * 512 + col] = f2b(v);
                else
                    Out[(size_t)row * 512 + col] = X[(size_t)row * 512 + col] + v;
            }
        }
    }
}

extern "C" void kernel_launch(void* const* d_in, const int* in_sizes, int n_in,
                              void* d_out, int out_size, void* d_ws, size_t ws_size,
                              hipStream_t stream) {
    const float* x     = (const float*)d_in[0];
    const float* W_in  = (const float*)d_in[1];
    const float* b_in  = (const float*)d_in[2];
    const float* W_out = (const float*)d_in[3];
    const float* b_out = (const float*)d_in[4];
    float* out = (float*)d_out;

    char* ws = (char*)d_ws;
    float*          cmf    = (float*)ws;                        // 8 KB
    int*            counts = (int*)(ws + 8192);                 // 8 KB
    int*            routes = (int*)(ws + 16384);                // 512 KB
    unsigned short* Wt_in  = (unsigned short*)(ws + 16384 + 524288);        // 512 KB
    unsigned short* Wt_out = (unsigned short*)(ws + 16384 + 2 * 524288);    // 512 KB
    unsigned short* h      = (unsigned short*)(ws + 16384 + 3 * 524288);    // 4 MB

    cantor_kernel<<<8, 256, 0, stream>>>(cmf);
    group_kernel<<<S_LEN, 64, 0, stream>>>(cmf, routes, counts);
    wt_kernel<<<128, 256, 0, stream>>>(W_in, Wt_in);
    wt_kernel<<<128, 256, 0, stream>>>(W_out, Wt_out);
    gemm_mfma<0><<<dim3(4, 32), 256, 0, stream>>>(x, nullptr, Wt_in, b_in,
                                                  nullptr, h, nullptr,
                                                  nullptr, nullptr);
    gemm_mfma<1><<<dim3(4, 32), 256, 0, stream>>>(nullptr, h, Wt_out, b_out,
                                                  x, nullptr, out,
                                                  routes, counts);
}

// Round 5
// 36.570 us; speedup vs baseline: 5.8860x; 1.4900x over previous
//
#include <hip/hip_runtime.h>
#include <hip/hip_bf16.h>

#define S_LEN 2048
#define K_NB  64

typedef __attribute__((ext_vector_type(8))) short bf16x8;
typedef __attribute__((ext_vector_type(4))) float f32x4;
typedef __attribute__((ext_vector_type(4))) unsigned int u32x4;

__device__ inline unsigned short f2b(float f) {
    unsigned u = __builtin_bit_cast(unsigned, f);
    return (unsigned short)((u + 0x7FFFu + ((u >> 16) & 1u)) >> 16);  // RNE
}

// ---------------------------------------------------------------------------
// prep: blocks 0..255 = W transpose+bf16 (both matrices); 256..263 = cantor.
// ---------------------------------------------------------------------------
__global__ __launch_bounds__(256) void prep_kernel(const float* __restrict__ W_in,
                                                   const float* __restrict__ W_out,
                                                   unsigned short* __restrict__ Wt_in,
                                                   unsigned short* __restrict__ Wt_out,
                                                   float* __restrict__ cmf) {
    int b = blockIdx.x;
    if (b < 256) {
        int t = b * 256 + threadIdx.x;          // 0..65535
        const float* W = (t & 32768) ? W_out : W_in;
        unsigned short* Wt = (t & 32768) ? Wt_out : Wt_in;
        int u = t & 32767;
        int n = u & 511, kc = (u >> 9) * 8;
        unsigned short tmp[8];
        #pragma unroll
        for (int j = 0; j < 8; ++j) tmp[j] = f2b(W[(size_t)(kc + j) * 512 + n]);
        *(u32x4*)(Wt + (size_t)n * 512 + kc) = *(u32x4*)tmp;
    } else {
        int s = (b - 256) * 256 + threadIdx.x;  // 0..2047
        float pos = ((float)s + 0.5f) * (1.0f / 2048.0f);
        float cm = 0.0f, scale = 1.0f, lvlw = 1.0f;
        #pragma unroll
        for (int k = 1; k <= 5; ++k) {
            scale *= 3.0f; lvlw *= 0.5f;
            float y = fmodf(pos * scale, 3.0f);
            float d0 = y - 0.5f, d1 = y - 1.5f, d2 = y - 2.5f;
            float l0 = -(d0 * d0) * 4.0f;   // /(0.25+1e-10) == *4 in fp32
            float l1 = -(d1 * d1) * 4.0f;
            float l2 = -(d2 * d2) * 4.0f;
            float m = fmaxf(l0, fmaxf(l1, l2));
            float e0 = (float)exp((double)(l0 - m));
            float e1 = (float)exp((double)(l1 - m));
            float e2 = (float)exp((double)(l2 - m));
            float sum = (e0 + e1) + e2;
            float p1 = e1 / sum, p2 = e2 / sum;
            cm += (p2 + 0.5f * p1) * lvlw;
        }
        cmf[s] = cm;
    }
}

// ---------------------------------------------------------------------------
// Wave-parallel exact-equality grouping (weights exactly 1/n over first
// min(n,64) equal-cm indices; all other softmax weights underflow to 0).
// ---------------------------------------------------------------------------
__global__ __launch_bounds__(64) void group_kernel(const float* __restrict__ cmf,
                                                   int* __restrict__ routes,
                                                   int* __restrict__ counts) {
    int s = blockIdx.x;
    int lane = threadIdx.x;
    float v = cmf[s];
    int n = 0;
    int* rt = routes + s * K_NB;
    for (int j0 = 0; j0 < S_LEN; j0 += 64) {
        float c = cmf[j0 + lane];
        bool m = (c == v);
        unsigned long long mask = __ballot(m);
        if (m) {
            int idx = n + __popcll(mask & ((1ull << lane) - 1ull));
            if (idx < K_NB) rt[idx] = j0 + lane;
        }
        n += __popcll(mask);
    }
    if (lane == 0) counts[s] = n < K_NB ? n : K_NB;
}

// ---------------------------------------------------------------------------
// bf16 MFMA GEMM, BM=64 x BN=128, BK=64, 4 waves (2x2), 256 blocks.
// Software-pipelined: next K-step's A/B prefetched to regs during compute.
// XOR-swizzled LDS (T2): byte ^= (row&7)<<4 kills ds_read_b128 conflicts.
// EPI==0: A = x fp32 (convert in-flight), out h = bf16(A@Wt_in^T + b_in)
// EPI==1: A = group-avg of h rows (n==1 fast path = copy),
//         out = X + (A@Wt_out^T + b_out)  fp32
// Frag layout verified (round 4 passed): A/B row|col=lane&15, k=(lane>>4)*8+j;
// D row=(lane>>4)*4+r, col=lane&15.
// ---------------------------------------------------------------------------
template <int EPI>
__global__ __launch_bounds__(256) void gemm_mfma(
    const float* __restrict__ Af, const unsigned short* __restrict__ Ab,
    const unsigned short* __restrict__ Bt, const float* __restrict__ bias,
    const float* __restrict__ X, unsigned short* __restrict__ Hb,
    float* __restrict__ Out,
    const int* __restrict__ routes, const int* __restrict__ counts) {
    __shared__ char lds[(64 + 128) * 64 * 2];   // A 8KB | B 16KB
    char* As = lds;
    char* Bs = lds + 64 * 64 * 2;
    const int tid = threadIdx.x;
    const int bn = blockIdx.x, bm = blockIdx.y;
    const int wid = tid >> 6, lane = tid & 63;
    const int wr = wid >> 1, wc = wid & 1;
    const int l15 = lane & 15, l4 = lane >> 4;

    const int arow = tid >> 2;           // 0..63
    const int akq  = (tid & 3) * 16;     // 0,16,32,48
    const int brow = tid >> 1;           // 0..127
    const int bkh  = (tid & 1) * 32;     // 0,32

    auto off = [](int row, int k) -> int {
        int o = row * 128 + k * 2;
        return o ^ ((row & 7) << 4);
    };

    const int grow = bm * 64 + arow;
    const float* arow_f = nullptr;
    int gn = 1; const int* grt = nullptr; float ginv = 1.0f; size_t hbase = 0;
    if (EPI == 0) {
        arow_f = Af + (size_t)grow * 512;
    } else {
        int gs = grow & (S_LEN - 1), gb = grow >> 11;
        gn = counts[gs];
        grt = routes + gs * K_NB;
        ginv = 1.0f / (float)gn;
        hbase = (size_t)gb * S_LEN * 512;
    }
    const unsigned short* bsrc = Bt + (size_t)(bn * 128 + brow) * 512 + bkh;

    u32x4 arg[2] = {};           // prefetched A (16 bf16)
    u32x4 brg[4] = {};           // prefetched B (32 bf16)

    auto load_a = [&](int k0, u32x4* dst) {
        if (EPI == 0) {
            const float* p = arow_f + k0 + akq;
            unsigned short tmp[16];
            #pragma unroll
            for (int i = 0; i < 4; ++i) {
                float4 v = *(const float4*)(p + i * 4);
                tmp[i*4+0] = f2b(v.x); tmp[i*4+1] = f2b(v.y);
                tmp[i*4+2] = f2b(v.z); tmp[i*4+3] = f2b(v.w);
            }
            dst[0] = *(u32x4*)&tmp[0];
            dst[1] = *(u32x4*)&tmp[8];
        } else if (gn == 1) {
            const unsigned short* p = Ab + (size_t)grow * 512 + k0 + akq;
            dst[0] = *(const u32x4*)(p);
            dst[1] = *(const u32x4*)(p + 8);
        } else {
            float av[16] = {};
            for (int e = 0; e < gn; ++e) {
                const unsigned short* p = Ab + hbase + (size_t)grt[e] * 512 + k0 + akq;
                #pragma unroll
                for (int half = 0; half < 2; ++half) {
                    u32x4 u = *(const u32x4*)(p + half * 8);
                    #pragma unroll
                    for (int q = 0; q < 4; ++q) {
                        unsigned w = u[q];
                        av[half*8 + q*2 + 0] += __builtin_bit_cast(float, w << 16);
                        av[half*8 + q*2 + 1] += __builtin_bit_cast(float, w & 0xFFFF0000u);
                    }
                }
            }
            unsigned short tmp[16];
            #pragma unroll
            for (int i = 0; i < 16; ++i) tmp[i] = f2b(av[i] * ginv);
            dst[0] = *(u32x4*)&tmp[0];
            dst[1] = *(u32x4*)&tmp[8];
        }
    };
    auto load_b = [&](int k0, u32x4* dst) {
        const unsigned short* p = bsrc + k0;
        #pragma unroll
        for (int i = 0; i < 4; ++i) dst[i] = *(const u32x4*)(p + i * 8);
    };

    f32x4 acc[2][4] = {};

    load_a(0, arg);
    load_b(0, brg);
    for (int k0 = 0; k0 < 512; k0 += 64) {
        // commit prefetched tile to LDS
        *(u32x4*)(As + off(arow, akq))     = arg[0];
        *(u32x4*)(As + off(arow, akq + 8)) = arg[1];
        #pragma unroll
        for (int i = 0; i < 4; ++i)
            *(u32x4*)(Bs + off(brow, bkh + i * 8)) = brg[i];
        __syncthreads();
        // prefetch next tile into regs (overlaps the MFMAs below)
        if (k0 + 64 < 512) {
            load_a(k0 + 64, arg);
            load_b(k0 + 64, brg);
        }
        // compute current tile
        #pragma unroll
        for (int kk = 0; kk < 2; ++kk) {
            const int kb = kk * 32 + l4 * 8;
            bf16x8 af[2], bg[4];
            #pragma unroll
            for (int m = 0; m < 2; ++m)
                af[m] = *(bf16x8*)(As + off(wr * 32 + m * 16 + l15, kb));
            #pragma unroll
            for (int n = 0; n < 4; ++n)
                bg[n] = *(bf16x8*)(Bs + off(wc * 64 + n * 16 + l15, kb));
            #pragma unroll
            for (int m = 0; m < 2; ++m)
                #pragma unroll
                for (int n = 0; n < 4; ++n)
                    acc[m][n] = __builtin_amdgcn_mfma_f32_16x16x32_bf16(
                        af[m], bg[n], acc[m][n], 0, 0, 0);
        }
        __syncthreads();
    }

    // epilogue
    float bv[4];
    #pragma unroll
    for (int n = 0; n < 4; ++n) bv[n] = bias[bn * 128 + wc * 64 + n * 16 + l15];
    #pragma unroll
    for (int m = 0; m < 2; ++m) {
        #pragma unroll
        for (int r = 0; r < 4; ++r) {
            int row = bm * 64 + wr * 32 + m * 16 + l4 * 4 + r;
            #pragma unroll
            for (int n = 0; n < 4; ++n) {
                int col = bn * 128 + wc * 64 + n * 16 + l15;
                float v = acc[m][n][r] + bv[n];
                if (EPI == 0)
                    Hb[(size_t)row * 512 + col] = f2b(v);
                else
                    Out[(size_t)row * 512 + col] = X[(size_t)row * 512 + col] + v;
            }
        }
    }
}

extern "C" void kernel_launch(void* const* d_in, const int* in_sizes, int n_in,
                              void* d_out, int out_size, void* d_ws, size_t ws_size,
                              hipStream_t stream) {
    const float* x     = (const float*)d_in[0];
    const float* W_in  = (const float*)d_in[1];
    const float* b_in  = (const float*)d_in[2];
    const float* W_out = (const float*)d_in[3];
    const float* b_out = (const float*)d_in[4];
    float* out = (float*)d_out;

    char* ws = (char*)d_ws;
    float*          cmf    = (float*)ws;                                 // 8 KB
    int*            counts = (int*)(ws + 8192);                          // 8 KB
    int*            routes = (int*)(ws + 16384);                         // 512 KB
    unsigned short* Wt_in  = (unsigned short*)(ws + 16384 + 524288);     // 512 KB
    unsigned short* Wt_out = (unsigned short*)(ws + 16384 + 2 * 524288); // 512 KB
    unsigned short* h      = (unsigned short*)(ws + 16384 + 3 * 524288); // 4 MB

    prep_kernel<<<264, 256, 0, stream>>>(W_in, W_out, Wt_in, Wt_out, cmf);
    group_kernel<<<S_LEN, 64, 0, stream>>>(cmf, routes, counts);
    gemm_mfma<0><<<dim3(4, 64), 256, 0, stream>>>(x, nullptr, Wt_in, b_in,
                                                  nullptr, h, nullptr,
                                                  nullptr, nullptr);
    gemm_mfma<1><<<dim3(4, 64), 256, 0, stream>>>(nullptr, h, Wt_out, b_out,
                                                  x, nullptr, out,
                                                  routes, counts);
}